// Round 11
// baseline (3085.103 us; speedup 1.0000x reference)
//
#include <hip/hip_runtime.h>
#include <hip/hip_bf16.h>

// GraphCastEdgeBlock fused persistent kernel for MI355X (gfx950).
// h = silu(LN(concat(ea, ns[src], nd[dst]) @ W1 + b1)); out = ea + h @ W2 + b2
// E=600000, N=50000, D=128, H=512, in=384. fp32 I/O; bf16 MFMA compute.
// Persistent 512 blocks (2/CU), MT=64, r7 compute skeleton. Cross-tile
// pipeline: next tile's gathers issued under GEMM2 passes (reg-staged by
// waves 0-3 whose acc is dead), written into the dead x region. LDS 81920B
// exactly: x 48K + act-half 32K, red/stats overlaid in dead regions.

#define E_TOTAL 600000
#define DD      128
#define HH      512
#define IND     384
#define MT      64
#define NT      9375    // E_TOTAL / MT
#define NBLK    512     // persistent blocks, 2 per CU

typedef __attribute__((ext_vector_type(8))) short bf16x8;
typedef __attribute__((ext_vector_type(4))) float f32x4;

__device__ __forceinline__ ushort f2bf(float f) {
    __hip_bfloat16 b = __float2bfloat16(f);
    return *reinterpret_cast<ushort*>(&b);
}
__device__ __forceinline__ uint pk2(float a, float b) {
    __hip_bfloat162 h = __float22bfloat162_rn(float2{a, b});
    return *reinterpret_cast<uint*>(&h);
}

template <int CTRL>
__device__ __forceinline__ float dpp_add(float x) {
    union { float f; int i; } a, b;
    a.f = x;
    b.i = __builtin_amdgcn_update_dpp(0, a.i, CTRL, 0xf, 0xf, true);
    return x + b.f;
}
__device__ __forceinline__ float row16_sum(float s) {
    s = dpp_add<0xB1>(s);    // quad_perm xor1
    s = dpp_add<0x4E>(s);    // quad_perm xor2
    s = dpp_add<0x124>(s);   // row_ror:4
    s = dpp_add<0x128>(s);   // row_ror:8
    return s;
}

// W1 [384][512] f32 -> W1t [512][384] bf16 ; W2 [512][128] f32 -> W2t [128][512] bf16
__global__ void prep_weights(const float* __restrict__ W1, const float* __restrict__ W2,
                             ushort* __restrict__ W1t, ushort* __restrict__ W2t) {
    int j = blockIdx.x * 256 + threadIdx.x;
    if (j < IND * HH) {
        int n = j / IND, k = j % IND;
        W1t[j] = f2bf(W1[k * HH + n]);
    }
    int j2 = j - IND * HH;
    if (j2 >= 0 && j2 < HH * DD) {
        int d2 = j2 / HH, k = j2 % HH;
        W2t[j2] = f2bf(W2[k * DD + d2]);
    }
}

// issue 12 float4 gathers for row r's concat-x (cols sg*48 .. sg*48+47)
__device__ __forceinline__ void issue_rowload(
    const float* __restrict__ ea, const float* __restrict__ ns,
    const float* __restrict__ nd, int e, int si, int di, int sg, float4* v)
{
    const float* pe = ea + (size_t)e * DD;
    const float* ps = ns + (size_t)si * DD - 128;
    const float* pd = nd + (size_t)di * DD - 256;
    #pragma unroll
    for (int j = 0; j < 12; ++j) {
        int c = sg * 48 + j * 4;
        const float* p = (c < 128) ? pe : (c < 256) ? ps : pd;
        v[j] = *(const float4*)(p + c);
    }
}
// convert + write them to swizzled x row (16B-chunk XOR swizzle)
__device__ __forceinline__ void write_rowx(ushort* xrow, int rs, int sg, const float4* v)
{
    #pragma unroll
    for (int j = 0; j < 12; ++j) {
        int c = sg * 48 + j * 4;
        int ch = c >> 3;
        uint2 u = { pk2(v[j].x, v[j].y), pk2(v[j].z, v[j].w) };
        *(uint2*)&xrow[((ch ^ rs) << 3) + (c & 7)] = u;
    }
}

__global__ __launch_bounds__(512, 4) void edge_persistent_kernel(
    const float* __restrict__ edge_attr,
    const float* __restrict__ nsrc,
    const float* __restrict__ ndst,
    const int*   __restrict__ eidx,
    const float* __restrict__ b1,
    const float* __restrict__ g1,
    const float* __restrict__ be1,
    const float* __restrict__ b2,
    const ushort* __restrict__ W1t,
    const ushort* __restrict__ W2t,
    float* __restrict__ out)
{
    __shared__ __align__(16) ushort xb[MT * IND];     // 49152 B, swizzled x
    __shared__ __align__(16) ushort actb[MT * 256];   // 32768 B, act half-buffer
    float* statsL = (float*)xb;     // [64][2] overlay: live barB..LN, then dead
    float* redL   = (float*)actb;   // [64][8]x2 overlay: live GEMM1end..barC

    const int tid  = threadIdx.x;
    const int lane = tid & 63;
    const int w    = tid >> 6;
    const int g    = lane >> 4;
    const int li   = lane & 15;
    const int sx   = li & 7;
    const int wn0  = w * 64;
    const int sr   = tid >> 3;      // staging row (w<4: 0..31)
    const int sg   = tid & 7;       // staging segment

    float b1v[4], g1v[4], bev[4];
    #pragma unroll
    for (int ni = 0; ni < 4; ++ni) {
        int c = wn0 + ni * 16 + li;
        b1v[ni] = b1[c]; g1v[ni] = g1[c]; bev[ni] = be1[c];
    }
    const float b2v = b2[w * 16 + li];
    const ushort* w1p = W1t + (size_t)(wn0 + li) * IND + g * 8;
    const ushort* w2p = W2t + (size_t)(w * 16 + li) * HH + g * 8;

    // ---- prologue: stage first tile fully (all 512 threads, rows tid>>3) ----
    {
        const int e0n = blockIdx.x * MT;
        int e = e0n + sr;
        int si = eidx[e], di = eidx[E_TOTAL + e];
        float4 v[12];
        issue_rowload(edge_attr, nsrc, ndst, e, si, di, sg, v);
        write_rowx(&xb[sr * IND], sr & 7, sg, v);
    }
    __syncthreads();   // A

    for (int t = blockIdx.x; t < NT; t += NBLK) {
        const int e0  = t * MT;
        const int tn  = t + NBLK;
        const bool hn = (tn < NT);
        const int e0n = tn * MT;

        // ---- GEMM1: h[64][512] = x @ W1 ----
        f32x4 acc[4][4];
        #pragma unroll
        for (int mi = 0; mi < 4; ++mi)
            #pragma unroll
            for (int ni = 0; ni < 4; ++ni)
                acc[mi][ni] = (f32x4){0.f, 0.f, 0.f, 0.f};

        bf16x8 B1b[2][4];
        #pragma unroll
        for (int ni = 0; ni < 4; ++ni) B1b[0][ni] = *(const bf16x8*)(w1p + ni * 16 * IND);
        #pragma unroll
        for (int ni = 0; ni < 4; ++ni) B1b[1][ni] = *(const bf16x8*)(w1p + ni * 16 * IND + 32);

        #pragma unroll
        for (int kb = 0; kb < 12; ++kb) {
            const int cur = kb & 1;
            const int swc = ((kb * 4 + g) ^ sx) << 3;
            bf16x8 a[4];
            #pragma unroll
            for (int mi = 0; mi < 4; ++mi)
                a[mi] = *(const bf16x8*)&xb[(mi * 16 + li) * IND + swc];
            __builtin_amdgcn_s_setprio(1);
            #pragma unroll
            for (int mi = 0; mi < 4; ++mi)
                #pragma unroll
                for (int ni = 0; ni < 4; ++ni)
                    acc[mi][ni] = __builtin_amdgcn_mfma_f32_16x16x32_bf16(
                        a[mi], B1b[cur][ni], acc[mi][ni], 0, 0, 0);
            __builtin_amdgcn_s_setprio(0);
            if (kb < 10) {
                #pragma unroll
                for (int ni = 0; ni < 4; ++ni)
                    B1b[cur][ni] = *(const bf16x8*)(w1p + ni * 16 * IND + (kb + 2) * 32);
            }
        }

        // ---- bias + row stats -> redL (overlaid on dead act) ----
        #pragma unroll
        for (int mi = 0; mi < 4; ++mi) {
            #pragma unroll
            for (int reg = 0; reg < 4; ++reg) {
                float s = 0.f, q = 0.f;
                #pragma unroll
                for (int ni = 0; ni < 4; ++ni) {
                    float h = acc[mi][ni][reg] + b1v[ni];
                    acc[mi][ni][reg] = h;
                    s += h;
                    q = fmaf(h, h, q);
                }
                s = row16_sum(s);
                q = row16_sum(q);
                if (li == 0) {
                    int row = mi * 16 + g * 4 + reg;
                    redL[row * 8 + w] = s;
                    redL[512 + row * 8 + w] = q;
                }
            }
        }
        __syncthreads();   // B

        if (tid < MT) {
            float s = 0.f, q = 0.f;
            #pragma unroll
            for (int i = 0; i < 8; ++i) { s += redL[tid * 8 + i]; q += redL[512 + tid * 8 + i]; }
            float mu  = s * (1.f / 512.f);
            float var = q * (1.f / 512.f) - mu * mu;
            statsL[tid * 2]     = mu;
            statsL[tid * 2 + 1] = rsqrtf(var + 1e-5f);
        }
        __syncthreads();   // C

        // ---- LN-h1 (waves 0-3 -> act cols 0..255) + B2 preload + ch1 eidx ----
        bf16x8 B2r[4];
        #pragma unroll
        for (int i = 0; i < 4; ++i) B2r[i] = *(const bf16x8*)(w2p + i * 32);

        int si1 = 0, di1 = 0;
        if (hn && w < 4) {
            int e = e0n + 32 + sr;
            si1 = eidx[e]; di1 = eidx[E_TOTAL + e];
        }
        if (w < 4) {
            #pragma unroll
            for (int mi = 0; mi < 4; ++mi) {
                #pragma unroll
                for (int reg = 0; reg < 4; ++reg) {
                    int row = mi * 16 + g * 4 + reg;
                    int rs  = row & 7;
                    float2 st = *(float2*)&statsL[row * 2];
                    #pragma unroll
                    for (int ni = 0; ni < 4; ++ni) {
                        float sc = st.y * g1v[ni];
                        float tc = fmaf(-st.x, sc, bev[ni]);
                        float xn = fmaf(acc[mi][ni][reg], sc, tc);
                        float av = xn * __builtin_amdgcn_rcpf(1.f + __expf(-xn));
                        int col = wn0 + ni * 16 + li;
                        actb[row * 256 + (((col >> 3) ^ rs) << 3) + (col & 7)] = f2bf(av);
                    }
                }
            }
        }
        __syncthreads();   // D

        // ---- GEMM2 pass 1 (k 0..255) + ch1 gather issue (rows 32..63) ----
        float4 sv[12];
        if (hn && w < 4)
            issue_rowload(edge_attr, nsrc, ndst, e0n + 32 + sr, si1, di1, sg, sv);

        f32x4 acc2[4];
        #pragma unroll
        for (int mi = 0; mi < 4; ++mi) acc2[mi] = (f32x4){0.f, 0.f, 0.f, 0.f};

        #pragma unroll
        for (int kb = 0; kb < 8; ++kb) {
            bf16x8 bf = B2r[kb & 3];
            B2r[kb & 3] = *(const bf16x8*)(w2p + (kb + 4) * 32);   // globals 4..11
            const int swc = ((kb * 4 + g) ^ sx) << 3;
            bf16x8 a2[4];
            #pragma unroll
            for (int mi = 0; mi < 4; ++mi)
                a2[mi] = *(const bf16x8*)&actb[(mi * 16 + li) * 256 + swc];
            __builtin_amdgcn_s_setprio(1);
            #pragma unroll
            for (int mi = 0; mi < 4; ++mi)
                acc2[mi] = __builtin_amdgcn_mfma_f32_16x16x32_bf16(a2[mi], bf, acc2[mi], 0, 0, 0);
            __builtin_amdgcn_s_setprio(0);
        }
        __syncthreads();   // E

        // ---- LN-h2 (waves 4-7 -> act cols 256..511, reused buffer);
        //      waves 0-3 write ch1 x rows 32..63 ----
        if (w >= 4) {
            #pragma unroll
            for (int mi = 0; mi < 4; ++mi) {
                #pragma unroll
                for (int reg = 0; reg < 4; ++reg) {
                    int row = mi * 16 + g * 4 + reg;
                    int rs  = row & 7;
                    float2 st = *(float2*)&statsL[row * 2];
                    #pragma unroll
                    for (int ni = 0; ni < 4; ++ni) {
                        float sc = st.y * g1v[ni];
                        float tc = fmaf(-st.x, sc, bev[ni]);
                        float xn = fmaf(acc[mi][ni][reg], sc, tc);
                        float av = xn * __builtin_amdgcn_rcpf(1.f + __expf(-xn));
                        int col = (wn0 - 256) + ni * 16 + li;
                        actb[row * 256 + (((col >> 3) ^ rs) << 3) + (col & 7)] = f2bf(av);
                    }
                }
            }
        } else if (hn) {
            write_rowx(&xb[(32 + sr) * IND], (32 + sr) & 7, sg, sv);
        }
        __syncthreads();   // F

        // ---- GEMM2 pass 2 (k 256..511) + ch2 gather issue (rows 0..31) + earr ----
        if (hn && w < 4) {
            int e = e0n + sr;
            int si0 = eidx[e], di0 = eidx[E_TOTAL + e];
            issue_rowload(edge_attr, nsrc, ndst, e, si0, di0, sg, sv);
        }
        float earr[16];
        #pragma unroll
        for (int mi = 0; mi < 4; ++mi)
            #pragma unroll
            for (int reg = 0; reg < 4; ++reg) {
                int row = mi * 16 + g * 4 + reg;
                earr[mi * 4 + reg] = edge_attr[(size_t)(e0 + row) * DD + w * 16 + li];
            }

        #pragma unroll
        for (int kb = 0; kb < 8; ++kb) {
            bf16x8 bf = B2r[kb & 3];                               // globals 8..15
            if (kb < 4)
                B2r[kb & 3] = *(const bf16x8*)(w2p + (kb + 12) * 32);
            const int swc = ((kb * 4 + g) ^ sx) << 3;
            bf16x8 a2[4];
            #pragma unroll
            for (int mi = 0; mi < 4; ++mi)
                a2[mi] = *(const bf16x8*)&actb[(mi * 16 + li) * 256 + swc];
            __builtin_amdgcn_s_setprio(1);
            #pragma unroll
            for (int mi = 0; mi < 4; ++mi)
                acc2[mi] = __builtin_amdgcn_mfma_f32_16x16x32_bf16(a2[mi], bf, acc2[mi], 0, 0, 0);
            __builtin_amdgcn_s_setprio(0);
        }

        // ---- epilogue: out = acc2 + b2 + ea; then ch2 x write (rows 0..31) ----
        #pragma unroll
        for (int mi = 0; mi < 4; ++mi) {
            #pragma unroll
            for (int reg = 0; reg < 4; ++reg) {
                int row = mi * 16 + g * 4 + reg;
                size_t o = (size_t)(e0 + row) * DD + w * 16 + li;
                out[o] = acc2[mi][reg] + b2v + earr[mi * 4 + reg];
            }
        }
        if (hn && w < 4)
            write_rowx(&xb[sr * IND], sr & 7, sg, sv);
        __syncthreads();   // A (next tile's x complete)
    }
}

extern "C" void kernel_launch(void* const* d_in, const int* in_sizes, int n_in,
                              void* d_out, int out_size, void* d_ws, size_t ws_size,
                              hipStream_t stream) {
    const float* edge_attr = (const float*)d_in[0];
    const float* nsrc      = (const float*)d_in[1];
    const float* ndst      = (const float*)d_in[2];
    const int*   eidx      = (const int*)d_in[3];
    const float* W1        = (const float*)d_in[4];
    const float* b1        = (const float*)d_in[5];
    const float* g1        = (const float*)d_in[6];
    const float* be1       = (const float*)d_in[7];
    const float* W2        = (const float*)d_in[8];
    const float* b2        = (const float*)d_in[9];
    float* out = (float*)d_out;

    ushort* W1t = (ushort*)d_ws;             // 512*384 bf16 = 384 KiB
    ushort* W2t = W1t + IND * HH;            // 128*512 bf16 = 128 KiB

    hipLaunchKernelGGL(prep_weights,
                       dim3((IND * HH + HH * DD + 255) / 256), dim3(256), 0, stream,
                       W1, W2, W1t, W2t);

    hipLaunchKernelGGL(edge_persistent_kernel,
                       dim3(NBLK), dim3(512), 0, stream,
                       edge_attr, nsrc, ndst, eidx, b1, g1, be1, b2, W1t, W2t, out);
}

// Round 12
// 659.979 us; speedup vs baseline: 4.6745x; 4.6745x over previous
//
#include <hip/hip_runtime.h>
#include <hip/hip_bf16.h>

// GraphCastEdgeBlock fused kernel for MI355X (gfx950).
// h = silu(LN(concat(ea, ns[src], nd[dst]) @ W1 + b1)); out = ea + h @ W2 + b2
// E=600000, N=50000, D=128, H=512, in=384. fp32 I/O; bf16 MFMA compute.
// r7 skeleton (MTILE=64, 8 waves, 16x16x32, spill-free) + GEMM2 B ring-6
// loaded post-LN (covers L2 latency) + nontemporal output stores (keep
// weights L2-resident).

#define E_TOTAL 600000
#define DD      128
#define HH      512
#define IND     384
#define MTILE   64
#define XS      520   // LDS row stride (bf16 elems); 1040 B

typedef __attribute__((ext_vector_type(8))) short bf16x8;
typedef __attribute__((ext_vector_type(4))) float f32x4;

__device__ __forceinline__ ushort f2bf(float f) {
    __hip_bfloat16 b = __float2bfloat16(f);
    return *reinterpret_cast<ushort*>(&b);
}

template <int CTRL>
__device__ __forceinline__ float dpp_add(float x) {
    union { float f; int i; } a, b;
    a.f = x;
    b.i = __builtin_amdgcn_update_dpp(0, a.i, CTRL, 0xf, 0xf, true);
    return x + b.f;
}
// sum across each 16-lane row (all lanes get the sum); pure VALU, no DS
__device__ __forceinline__ float row16_sum(float s) {
    s = dpp_add<0xB1>(s);    // quad_perm xor1
    s = dpp_add<0x4E>(s);    // quad_perm xor2
    s = dpp_add<0x124>(s);   // row_ror:4
    s = dpp_add<0x128>(s);   // row_ror:8
    return s;
}

// W1 [384][512] f32 -> W1t [512][384] bf16 ; W2 [512][128] f32 -> W2t [128][512] bf16
__global__ void prep_weights(const float* __restrict__ W1, const float* __restrict__ W2,
                             ushort* __restrict__ W1t, ushort* __restrict__ W2t) {
    int j = blockIdx.x * 256 + threadIdx.x;
    if (j < IND * HH) {
        int n = j / IND, k = j % IND;
        W1t[j] = f2bf(W1[k * HH + n]);
    }
    int j2 = j - IND * HH;
    if (j2 >= 0 && j2 < HH * DD) {
        int d2 = j2 / HH, k = j2 % HH;
        W2t[j2] = f2bf(W2[k * DD + d2]);
    }
}

__global__ __launch_bounds__(512, 4) void edge_block_kernel(
    const float* __restrict__ edge_attr,
    const float* __restrict__ nsrc,
    const float* __restrict__ ndst,
    const int*   __restrict__ eidx,
    const float* __restrict__ b1,
    const float* __restrict__ g1,
    const float* __restrict__ be1,
    const float* __restrict__ b2,
    const ushort* __restrict__ W1t,
    const ushort* __restrict__ W2t,
    float* __restrict__ out)
{
    __shared__ __align__(16) ushort xbuf[MTILE * XS];  // 66560 B (x, then act)
    __shared__ float red_s[MTILE][8];
    __shared__ float red_q[MTILE][8];
    __shared__ __align__(8) float stats[MTILE][2];

    const int tid  = threadIdx.x;
    const int e0   = blockIdx.x * MTILE;
    const int lane = tid & 63;
    const int w    = tid >> 6;          // wave 0..7
    const int g    = lane >> 4;         // quarter-wave 0..3
    const int li   = lane & 15;

    // ---- 1) stage x tile [64][384] -> LDS bf16; eidx hoisted ----
    {
        const int l32 = tid & 31, grp = tid >> 5;    // 16 groups of 32 lanes
        int si[4], di[4];
        #pragma unroll
        for (int it = 0; it < 4; ++it) {
            const int e = e0 + grp + it * 16;
            si[it] = eidx[e];
            di[it] = eidx[E_TOTAL + e];
        }
        #pragma unroll
        for (int it = 0; it < 4; ++it) {
            const int r = grp + it * 16;
            const int e = e0 + r;
            float4 ea = *(const float4*)&edge_attr[(size_t)e * DD + l32 * 4];
            float4 sf = *(const float4*)&nsrc[(size_t)si[it] * DD + l32 * 4];
            float4 df = *(const float4*)&ndst[(size_t)di[it] * DD + l32 * 4];
            ushort* row = &xbuf[r * XS];
            ushort4 ua = { f2bf(ea.x), f2bf(ea.y), f2bf(ea.z), f2bf(ea.w) };
            ushort4 us = { f2bf(sf.x), f2bf(sf.y), f2bf(sf.z), f2bf(sf.w) };
            ushort4 ud = { f2bf(df.x), f2bf(df.y), f2bf(df.z), f2bf(df.w) };
            *(ushort4*)&row[  0 + l32 * 4] = ua;
            *(ushort4*)&row[128 + l32 * 4] = us;
            *(ushort4*)&row[256 + l32 * 4] = ud;
        }
    }
    __syncthreads();   // A

    // ---- 2) GEMM1: h[64][512] = x @ W1; wave w owns cols [w*64, w*64+64) ----
    const int wn0 = w * 64;
    f32x4 acc[4][4];
    #pragma unroll
    for (int mi = 0; mi < 4; ++mi)
        #pragma unroll
        for (int ni = 0; ni < 4; ++ni)
            acc[mi][ni] = (f32x4){0.f, 0.f, 0.f, 0.f};

    const ushort* w1p = W1t + (size_t)(wn0 + li) * IND + g * 8;

    bf16x8 B1b[2][4];
    #pragma unroll
    for (int ni = 0; ni < 4; ++ni) B1b[0][ni] = *(const bf16x8*)(w1p + ni * 16 * IND);
    #pragma unroll
    for (int ni = 0; ni < 4; ++ni) B1b[1][ni] = *(const bf16x8*)(w1p + ni * 16 * IND + 32);

    #pragma unroll
    for (int kb = 0; kb < 12; ++kb) {
        const int cur = kb & 1;                  // compile-time after unroll
        const int ko  = kb * 32 + g * 8;
        bf16x8 a[4];
        #pragma unroll
        for (int mi = 0; mi < 4; ++mi)
            a[mi] = *(const bf16x8*)&xbuf[(mi * 16 + li) * XS + ko];
        __builtin_amdgcn_s_setprio(1);
        #pragma unroll
        for (int mi = 0; mi < 4; ++mi)
            #pragma unroll
            for (int ni = 0; ni < 4; ++ni)
                acc[mi][ni] = __builtin_amdgcn_mfma_f32_16x16x32_bf16(
                    a[mi], B1b[cur][ni], acc[mi][ni], 0, 0, 0);
        __builtin_amdgcn_s_setprio(0);
        if (kb < 10) {                           // prefetch depth 2
            #pragma unroll
            for (int ni = 0; ni < 4; ++ni)
                B1b[cur][ni] = *(const bf16x8*)(w1p + ni * 16 * IND + (kb + 2) * 32);
        }
    }

    // ---- 3) bias + row stats via DPP row-reduce ----
    float b1v[4], g1v[4], bev[4];
    #pragma unroll
    for (int ni = 0; ni < 4; ++ni) {
        int c = wn0 + ni * 16 + li;
        b1v[ni] = b1[c]; g1v[ni] = g1[c]; bev[ni] = be1[c];
    }

    #pragma unroll
    for (int mi = 0; mi < 4; ++mi) {
        #pragma unroll
        for (int reg = 0; reg < 4; ++reg) {
            float s = 0.f, q = 0.f;
            #pragma unroll
            for (int ni = 0; ni < 4; ++ni) {
                float h = acc[mi][ni][reg] + b1v[ni];
                acc[mi][ni][reg] = h;
                s += h;
                q = fmaf(h, h, q);
            }
            s = row16_sum(s);
            q = row16_sum(q);
            if (li == 0) {
                int row = mi * 16 + g * 4 + reg;
                red_s[row][w] = s;
                red_q[row][w] = q;
            }
        }
    }
    __syncthreads();   // B

    if (tid < MTILE) {
        float s = 0.f, q = 0.f;
        #pragma unroll
        for (int i = 0; i < 8; ++i) { s += red_s[tid][i]; q += red_q[tid][i]; }
        float mu  = s * (1.f / 512.f);
        float var = q * (1.f / 512.f) - mu * mu;
        stats[tid][0] = mu;
        stats[tid][1] = rsqrtf(var + 1e-5f);
    }
    __syncthreads();   // C

    // ---- 4) LN + SiLU (folded affine, rcp silu) -> act bf16 in LDS ----
    #pragma unroll
    for (int mi = 0; mi < 4; ++mi) {
        #pragma unroll
        for (int reg = 0; reg < 4; ++reg) {
            int row = mi * 16 + g * 4 + reg;
            float2 st = *(float2*)&stats[row][0];     // {mu, rstd}
            #pragma unroll
            for (int ni = 0; ni < 4; ++ni) {
                float sc = st.y * g1v[ni];                       // rstd*gamma
                float tc = fmaf(-st.x, sc, bev[ni]);             // beta - mu*sc
                float xn = fmaf(acc[mi][ni][reg], sc, tc);
                float ex = __expf(-xn);
                float a  = xn * __builtin_amdgcn_rcpf(1.f + ex); // silu
                xbuf[row * XS + wn0 + ni * 16 + li] = f2bf(a);
            }
        }
    }

    // ---- 5) B2 ring-6 preload (24 VGPR; acc dead after LN) ----
    const ushort* w2p = W2t + (size_t)(w * 16 + li) * HH + g * 8;
    bf16x8 B2r[6];
    #pragma unroll
    for (int i = 0; i < 6; ++i) B2r[i] = *(const bf16x8*)(w2p + i * 32);

    // residual loads (latency hides under barrier + GEMM2)
    float earr[4][4];
    #pragma unroll
    for (int mi = 0; mi < 4; ++mi)
        #pragma unroll
        for (int reg = 0; reg < 4; ++reg) {
            int row = mi * 16 + g * 4 + reg;
            earr[mi][reg] = edge_attr[(size_t)(e0 + row) * DD + w * 16 + li];
        }
    __syncthreads();   // D

    // ---- 6) GEMM2: out[64][128] = act @ W2; ring-6 streamed B ----
    f32x4 acc2[4];
    #pragma unroll
    for (int mi = 0; mi < 4; ++mi) acc2[mi] = (f32x4){0.f, 0.f, 0.f, 0.f};

    #pragma unroll
    for (int kb = 0; kb < 16; ++kb) {
        const int cur = kb % 6;                  // compile-time after unroll
        bf16x8 bf = B2r[cur];
        if (kb < 10)
            B2r[cur] = *(const bf16x8*)(w2p + (kb + 6) * 32);
        const int ko = kb * 32 + g * 8;
        bf16x8 a2[4];
        #pragma unroll
        for (int mi = 0; mi < 4; ++mi)
            a2[mi] = *(const bf16x8*)&xbuf[(mi * 16 + li) * XS + ko];
        __builtin_amdgcn_s_setprio(1);
        #pragma unroll
        for (int mi = 0; mi < 4; ++mi)
            acc2[mi] = __builtin_amdgcn_mfma_f32_16x16x32_bf16(a2[mi], bf, acc2[mi], 0, 0, 0);
        __builtin_amdgcn_s_setprio(0);
    }

    // ---- 7) epilogue: nontemporal direct stores, out = acc2 + b2 + ea(regs) ----
    const float b2v = b2[w * 16 + li];
    #pragma unroll
    for (int mi = 0; mi < 4; ++mi) {
        #pragma unroll
        for (int reg = 0; reg < 4; ++reg) {
            int row = mi * 16 + g * 4 + reg;
            size_t o = (size_t)(e0 + row) * DD + w * 16 + li;
            __builtin_nontemporal_store(acc2[mi][reg] + b2v + earr[mi][reg], &out[o]);
        }
    }
}

extern "C" void kernel_launch(void* const* d_in, const int* in_sizes, int n_in,
                              void* d_out, int out_size, void* d_ws, size_t ws_size,
                              hipStream_t stream) {
    const float* edge_attr = (const float*)d_in[0];
    const float* nsrc      = (const float*)d_in[1];
    const float* ndst      = (const float*)d_in[2];
    const int*   eidx      = (const int*)d_in[3];
    const float* W1        = (const float*)d_in[4];
    const float* b1        = (const float*)d_in[5];
    const float* g1        = (const float*)d_in[6];
    const float* be1       = (const float*)d_in[7];
    const float* W2        = (const float*)d_in[8];
    const float* b2        = (const float*)d_in[9];
    float* out = (float*)d_out;

    ushort* W1t = (ushort*)d_ws;             // 512*384 bf16 = 384 KiB
    ushort* W2t = W1t + IND * HH;            // 128*512 bf16 = 128 KiB

    hipLaunchKernelGGL(prep_weights,
                       dim3((IND * HH + HH * DD + 255) / 256), dim3(256), 0, stream,
                       W1, W2, W1t, W2t);

    hipLaunchKernelGGL(edge_block_kernel,
                       dim3(E_TOTAL / MTILE), dim3(512), 0, stream,
                       edge_attr, nsrc, ndst, eidx, b1, g1, be1, b2, W1t, W2t, out);
}